// Round 12
// baseline (184.997 us; speedup 1.0000x reference)
//
#include <hip/hip_runtime.h>
#include <math.h>

#define NFFT 256
#define NBINS 129
#define HOP 64
#define NFRAMES 65
#define NB 64
#define LX 4096
#define LH 2048
#define LY 1024
#define NCH 64
#define NBR 3
#define NE 8

#define PART_STRIDE 132
#define PART_BYTES (NB * NFRAMES * PART_STRIDE * 4)   // 2,196,480
#define WTF_OFF 2197504             // bf16 A-fragment weights
#define WTF_PER 98304               // bf16 elements per branch
#define IW_OFF 2787328              // inds/wts

typedef __attribute__((ext_vector_type(8))) short short8;   // 8 bf16
typedef __attribute__((ext_vector_type(4))) float floatx4;

__device__ __forceinline__ unsigned short bf16r(float f) {  // round-nearest-even
    unsigned u = __builtin_bit_cast(unsigned, f);
    u += 0x7FFFu + ((u >> 16) & 1u);
    return (unsigned short)(u >> 16);
}

// ---------------- STFT: one frame/block, 4-way split phasor DFT ------------
// grid (65 frames, 64 batch), 128 threads. Direct row writes (no atomics,
// no memset). Chunk j starts at phase k*j*pi/2 -> sign-select recombine.
__global__ __launch_bounds__(128) void stft_kernel(
    const float* __restrict__ x, float* __restrict__ part) {
    __shared__ float xw[NFFT];
    const int f = blockIdx.x, b = blockIdx.y;
    const int tid = threadIdx.x;

    for (int n = tid; n < NFFT; n += 128) {
        float a2 = (float)(2.0 * 3.14159265358979323846 / 256.0) * (float)n;
        float sn, cn;
        sincosf(a2, &sn, &cn);
        float win = 0.5f - 0.5f * cn;             // Hann
        int q = f * HOP + n - 128;
        int xi = q < 0 ? -q : (q >= LX ? (2 * LX - 2 - q) : q);  // reflect
        xw[n] = x[b * LX + xi] * win;
    }
    __syncthreads();

    const int k = tid;                            // bin 0..127
    float ang = (float)(2.0 * 3.14159265358979323846 / 256.0) * (float)k;
    float s1, c1;
    sincosf(ang, &s1, &c1);

    float A0 = 0.f, B0 = 0.f, A1 = 0.f, B1 = 0.f;
    float A2 = 0.f, B2 = 0.f, A3 = 0.f, B3 = 0.f;
    float c0 = 1.f, s0 = 0.f, cc1 = 1.f, ss1 = 0.f;
    float cc2 = 1.f, ss2 = 0.f, cc3 = 1.f, ss3 = 0.f;
    float rNe = 0.f, rNo = 0.f;

#pragma unroll 4
    for (int mq = 0; mq < 16; ++mq) {
        float4 v0 = *(const float4*)&xw[4 * mq];
        float4 v1 = *(const float4*)&xw[64 + 4 * mq];
        float4 v2 = *(const float4*)&xw[128 + 4 * mq];
        float4 v3 = *(const float4*)&xw[192 + 4 * mq];
        float e0[4] = {v0.x, v0.y, v0.z, v0.w};
        float e1[4] = {v1.x, v1.y, v1.z, v1.w};
        float e2[4] = {v2.x, v2.y, v2.z, v2.w};
        float e3[4] = {v3.x, v3.y, v3.z, v3.w};
#pragma unroll
        for (int mm = 0; mm < 4; ++mm) {
            float t;
            A0 = fmaf(e0[mm], c0, A0);  B0 = fmaf(e0[mm], s0, B0);
            A1 = fmaf(e1[mm], cc1, A1); B1 = fmaf(e1[mm], ss1, B1);
            A2 = fmaf(e2[mm], cc2, A2); B2 = fmaf(e2[mm], ss2, B2);
            A3 = fmaf(e3[mm], cc3, A3); B3 = fmaf(e3[mm], ss3, B3);
            if ((mm & 1) == 0) rNe += e0[mm] + e1[mm] + e2[mm] + e3[mm];
            else               rNo += e0[mm] + e1[mm] + e2[mm] + e3[mm];
            t = c0 * c1 - s0 * s1;   s0 = fmaf(c0, s1, s0 * c1);   c0 = t;
            t = cc1 * c1 - ss1 * s1; ss1 = fmaf(cc1, s1, ss1 * c1); cc1 = t;
            t = cc2 * c1 - ss2 * s1; ss2 = fmaf(cc2, s1, ss2 * c1); cc2 = t;
            t = cc3 * c1 - ss3 * s1; ss3 = fmaf(cc3, s1, ss3 * c1); cc3 = t;
        }
    }

    float re = A0, im = B0;
    float Aj[3] = {A1, A2, A3};
    float Bj[3] = {B1, B2, B3};
#pragma unroll
    for (int j = 1; j < 4; ++j) {
        int ph = (j * k) & 3;
        float cf = (ph == 0) ? 1.f : (ph == 2) ? -1.f : 0.f;
        float sf = (ph == 1) ? 1.f : (ph == 3) ? -1.f : 0.f;
        re += cf * Aj[j - 1] - sf * Bj[j - 1];
        im += sf * Aj[j - 1] + cf * Bj[j - 1];
    }

    float* prow = part + (b * NFRAMES + f) * PART_STRIDE;
    prow[k] = sqrtf(re * re + im * im);
    if (tid == 0) prow[128] = fabsf(rNe - rNo);
}

// ---------------- Gating MLP + top-2 softmax + wTf build ----------------
__global__ __launch_bounds__(256) void gating_kernel(
    const float* __restrict__ part,
    const float* __restrict__ Wg1, const float* __restrict__ bg1,
    const float* __restrict__ Wg2, const float* __restrict__ bg2,
    const float* __restrict__ Wg3, const float* __restrict__ bg3,
    const float* __restrict__ wb3, const float* __restrict__ wb5,
    const float* __restrict__ wb7, unsigned short* __restrict__ wTf,
    int* __restrict__ inds, float* __restrict__ wts) {
    __shared__ float pl[NBINS];
    __shared__ float h1[256];
    __shared__ float h2[128];
    __shared__ float lg[NE];
    const int b = blockIdx.x, tid = threadIdx.x;

    // build wTf[br][e][mw][i][kb][lane][j] in MFMA A-fragment order:
    //   c2 = mw*16 + (lane&15), cl = kb*32 + (lane>>4)*8 + j
    for (int fi = b * 256 + tid; fi < 3 * WTF_PER; fi += NB * 256) {
        int br = fi / WTF_PER, r = fi % WTF_PER;
        int e = r / 12288;
        int r2 = r % 12288;
        int mw = r2 / 3072;
        int r3 = r2 % 3072;
        int i = r3 / 1024;
        int r4 = r3 % 1024;
        int kb = r4 / 512;
        int r5 = r4 % 512;
        int lane = r5 / 8, j = r5 % 8;
        int c2 = mw * 16 + (lane & 15);
        int cl = kb * 32 + (lane >> 4) * 8 + j;
        const float* src = (br == 0) ? wb3 : (br == 1) ? wb5 : wb7;
        wTf[fi] = bf16r(src[((e * 64 + c2) * 64 + cl) * 3 + i]);
    }

    if (tid < NBINS) {
        float s = 0.f;
        for (int f = 0; f < NFRAMES; ++f)
            s += part[(b * NFRAMES + f) * PART_STRIDE + tid];
        pl[tid] = s * (1.0f / (float)NFRAMES);
    }
    __syncthreads();
    {
        float s = bg1[tid];
        for (int kk = 0; kk < NBINS; ++kk) s += pl[kk] * Wg1[kk * 256 + tid];
        h1[tid] = fmaxf(s, 0.f);
    }
    __syncthreads();
    if (tid < 128) {
        float s = bg2[tid];
        for (int kk = 0; kk < 256; ++kk) s += h1[kk] * Wg2[kk * 128 + tid];
        h2[tid] = fmaxf(s, 0.f);
    }
    __syncthreads();
    if (tid < NE) {
        float s = bg3[tid];
        for (int kk = 0; kk < 128; ++kk) s += h2[kk] * Wg3[kk * NE + tid];
        lg[tid] = s;
    }
    __syncthreads();
    if (tid == 0) {
        int i0 = 0;
        float v0 = lg[0];
        for (int i = 1; i < NE; ++i)
            if (lg[i] > v0) { v0 = lg[i]; i0 = i; }
        int i1 = -1;
        float v1 = -3.0e38f;
        for (int i = 0; i < NE; ++i) {
            if (i == i0) continue;
            if (lg[i] > v1) { v1 = lg[i]; i1 = i; }
        }
        float e1 = expf(v1 - v0);
        float w0 = 1.f / (1.f + e1);
        inds[b * 2 + 0] = i0;
        inds[b * 2 + 1] = i1;
        wts[b * 2 + 0] = w0;
        wts[b * 2 + 1] = e1 * w0;
    }
}

// ---------------- Expert path: fp32 conv1 -> bf16 MFMA conv2 ----------------
// grid (u-tiles=8 of 128, branch=3, batch=64), 512 threads (8 waves).
#define UT 128
#define HPR 68           // shorts per hp row (64 + 4 pad)
#define HROWS 258

template <int KSZ>
__device__ __forceinline__ void phaseA_rows(
    const float* __restrict__ xp, const float* wr, float bv, short* hp,
    int tb, int nrow, int t0, int x0) {
    const int lane_cl = threadIdx.x & 63;
    int base = x0 + 8 * tb;              // wave-uniform
    float xr[16];
    if (base >= 0 && base + 15 < LX) {
#pragma unroll
        for (int ii = 0; ii < 16; ++ii) xr[ii] = xp[base + ii];
    } else {
#pragma unroll
        for (int ii = 0; ii < 16; ++ii) {
            int xi = base + ii;
            xr[ii] = (xi >= 0 && xi < LX) ? xp[xi] : 0.f;
        }
    }
#pragma unroll
    for (int m = 0; m < 4; ++m) {
        if (m >= nrow) break;
        int tl = 4 * tb + m;
        int t = t0 + tl;
        float s = bv;
#pragma unroll
        for (int i = 0; i < KSZ; ++i) s += wr[i] * xr[2 * m + i];
        float h = (t >= 0 && t < LH) ? fmaxf(s, 0.f) : 0.f;
        hp[tl * HPR + lane_cl] = (short)bf16r(h);
    }
}

template <int KSZ>
__device__ __attribute__((always_inline)) void expert_body(
    const float* __restrict__ x,
    const float* __restrict__ wa, const float* __restrict__ ba,
    const float* __restrict__ bb, const unsigned short* __restrict__ wTfbr,
    const int* __restrict__ inds, const float* __restrict__ wts,
    float* __restrict__ out, int br, short* hp) {
    const int u0 = blockIdx.x * UT;
    const int b = blockIdx.z;
    const int tid = threadIdx.x;
    const int lane = tid & 63;
    const int quad = lane >> 4;
    const int l15 = lane & 15;
    const int wv = __builtin_amdgcn_readfirstlane(tid >> 6);
    const int mw = wv & 3;           // M-tile (c2 block of 16)
    const int nh = wv >> 2;          // N-half (4 N-tiles each)
    const int pad = KSZ >> 1;
    const int t0 = 2 * u0 - 1;
    const int x0 = 2 * t0 - pad;

    const float* xp = x + b * LX;

    float fin[4][4];
#pragma unroll
    for (int q = 0; q < 4; ++q)
#pragma unroll
        for (int r = 0; r < 4; ++r) fin[q][r] = 0.f;

#pragma unroll 1
    for (int slot = 0; slot < 2; ++slot) {
        const int e = __builtin_amdgcn_readfirstlane(inds[b * 2 + slot]);
        const float wj = wts[b * 2 + slot];

        // first-conv weights for this lane's channel (cl = lane)
        float wr[KSZ];
#pragma unroll
        for (int i = 0; i < KSZ; ++i) wr[i] = wa[(e * NCH + lane) * KSZ + i];
        const float bv = ba[e * NCH + lane];

        __syncthreads();   // protect hp from previous slot's phase C readers

        // ---- phase A: rows 0..255 (8 uniform iters), + wv0 tail 256..257 ----
#pragma unroll 2
        for (int it = 0; it < 8; ++it)
            phaseA_rows<KSZ>(xp, wr, bv, hp, wv + 8 * it, 4, t0, x0);
        if (wv == 0)
            phaseA_rows<KSZ>(xp, wr, bv, hp, 64, 2, t0, x0);
        __syncthreads();

        // ---- phase C: MFMA GEMM ----
        float br4[4];
#pragma unroll
        for (int r = 0; r < 4; ++r)
            br4[r] = bb[e * NCH + mw * 16 + quad * 4 + r];

        short8 af[3][2];
        {
            const unsigned short* wbase =
                wTfbr + e * 12288 + mw * 3072 + lane * 8;
#pragma unroll
            for (int i = 0; i < 3; ++i)
#pragma unroll
                for (int kb = 0; kb < 2; ++kb)
                    af[i][kb] = *(const short8*)&wbase[i * 1024 + kb * 512];
        }

#pragma unroll 2
        for (int q = 0; q < 4; ++q) {
            int nt = nh * 4 + q;
            int nb = nt * 16 + l15;          // local u (B-layout n = lane&15)
            floatx4 acc = {br4[0], br4[1], br4[2], br4[3]};
#pragma unroll
            for (int i = 0; i < 3; ++i) {
                int tl = 2 * nb + i;         // B row
#pragma unroll
                for (int kb = 0; kb < 2; ++kb) {
                    int sb = tl * HPR + kb * 32 + quad * 8;
                    union { short8 v; unsigned long long q2[2]; } B;
                    B.q2[0] = *(const unsigned long long*)&hp[sb];
                    B.q2[1] = *(const unsigned long long*)&hp[sb + 4];
                    acc = __builtin_amdgcn_mfma_f32_16x16x32_bf16(
                        af[i][kb], B.v, acc, 0, 0, 0);
                }
            }
#pragma unroll
            for (int r = 0; r < 4; ++r)
                fin[q][r] += wj * fmaxf(acc[r], 0.f);
        }
    }

#pragma unroll
    for (int q = 0; q < 4; ++q) {
        int u = u0 + (nh * 4 + q) * 16 + l15;
#pragma unroll
        for (int r = 0; r < 4; ++r) {
            int c2 = mw * 16 + quad * 4 + r;
            out[(long)(b * 192 + br * 64 + c2) * LY + u] = fin[q][r];
        }
    }
}

__global__ __launch_bounds__(512, 2) void expert_kernel(
    const float* __restrict__ x,
    const float* __restrict__ wa3, const float* __restrict__ ba3,
    const float* __restrict__ bb3,
    const float* __restrict__ wa5, const float* __restrict__ ba5,
    const float* __restrict__ bb5,
    const float* __restrict__ wa7, const float* __restrict__ ba7,
    const float* __restrict__ bb7,
    const unsigned short* __restrict__ wTf,
    const int* __restrict__ inds, const float* __restrict__ wts,
    float* __restrict__ out) {
    __shared__ short hp[HROWS * HPR];      // 35.1 KB

    const int br = blockIdx.y;
    if (br == 0)
        expert_body<3>(x, wa3, ba3, bb3, wTf, inds, wts, out, 0, hp);
    else if (br == 1)
        expert_body<5>(x, wa5, ba5, bb5, wTf + WTF_PER, inds, wts, out, 1, hp);
    else
        expert_body<7>(x, wa7, ba7, bb7, wTf + 2 * WTF_PER, inds, wts, out, 2, hp);
}

extern "C" void kernel_launch(void* const* d_in, const int* in_sizes, int n_in,
                              void* d_out, int out_size, void* d_ws, size_t ws_size,
                              hipStream_t stream) {
    const float* x   = (const float*)d_in[0];
    const float* Wg1 = (const float*)d_in[1];
    const float* bg1 = (const float*)d_in[2];
    const float* Wg2 = (const float*)d_in[3];
    const float* bg2 = (const float*)d_in[4];
    const float* Wg3 = (const float*)d_in[5];
    const float* bg3 = (const float*)d_in[6];
    const float* wa3 = (const float*)d_in[7];
    const float* ba3 = (const float*)d_in[8];
    const float* wb3 = (const float*)d_in[9];
    const float* bb3 = (const float*)d_in[10];
    const float* wa5 = (const float*)d_in[11];
    const float* ba5 = (const float*)d_in[12];
    const float* wb5 = (const float*)d_in[13];
    const float* bb5 = (const float*)d_in[14];
    const float* wa7 = (const float*)d_in[15];
    const float* ba7 = (const float*)d_in[16];
    const float* wb7 = (const float*)d_in[17];
    const float* bb7 = (const float*)d_in[18];

    float* part = (float*)d_ws;
    unsigned short* wTf = (unsigned short*)((char*)d_ws + WTF_OFF);
    int* inds = (int*)((char*)d_ws + IW_OFF);
    float* wts = (float*)((char*)d_ws + IW_OFF + 512);

    stft_kernel<<<dim3(NFRAMES, NB), 128, 0, stream>>>(x, part);
    gating_kernel<<<NB, 256, 0, stream>>>(part, Wg1, bg1, Wg2, bg2, Wg3, bg3,
                                          wb3, wb5, wb7, wTf, inds, wts);
    expert_kernel<<<dim3(LY / UT, NBR, NB), 512, 0, stream>>>(
        x, wa3, ba3, bb3, wa5, ba5, bb5, wa7, ba7, bb7, wTf,
        inds, wts, (float*)d_out);
}

// Round 13
// 177.207 us; speedup vs baseline: 1.0440x; 1.0440x over previous
//
#include <hip/hip_runtime.h>
#include <math.h>

#define NFFT 256
#define NBINS 129
#define HOP 64
#define NFRAMES 65
#define NB 64
#define LX 4096
#define LH 2048
#define LY 1024
#define NCH 64
#define NBR 3
#define NE 8

#define PART_STRIDE 132
#define WTF_OFF 2197504             // bf16 A-fragment weights
#define WTF_PER 98304               // bf16 elements per branch
#define IW_OFF 2787328              // inds/wts

typedef __attribute__((ext_vector_type(8))) short short8;   // 8 bf16
typedef __attribute__((ext_vector_type(4))) float floatx4;

__device__ __forceinline__ unsigned short bf16r(float f) {  // round-nearest-even
    unsigned u = __builtin_bit_cast(unsigned, f);
    u += 0x7FFFu + ((u >> 16) & 1u);
    return (unsigned short)(u >> 16);
}

// ---------------- STFT: one frame/block + wTf gather ------------
// grid (65 frames, 64 batch), 128 threads. Direct row writes, no atomics.
__global__ __launch_bounds__(128) void stft_kernel(
    const float* __restrict__ x,
    const float* __restrict__ wb3, const float* __restrict__ wb5,
    const float* __restrict__ wb7, unsigned short* __restrict__ wTf,
    float* __restrict__ part) {
    __shared__ float xw[NFFT];
    const int f = blockIdx.x, b = blockIdx.y;
    const int tid = threadIdx.x;

    // one wTf element per thread (532k threads >= 295k elements)
    {
        int fi = (b * NFRAMES + f) * 128 + tid;
        if (fi < 3 * WTF_PER) {
            int br = fi / WTF_PER, r = fi % WTF_PER;
            int e = r / 12288;
            int r2 = r % 12288;
            int mw = r2 / 3072;
            int r3 = r2 % 3072;
            int i = r3 / 1024;
            int r4 = r3 % 1024;
            int kb = r4 / 512;
            int r5 = r4 % 512;
            int lane = r5 / 8, j = r5 % 8;
            int c2 = mw * 16 + (lane & 15);
            int cl = kb * 32 + (lane >> 4) * 8 + j;
            const float* src = (br == 0) ? wb3 : (br == 1) ? wb5 : wb7;
            wTf[fi] = bf16r(src[((e * 64 + c2) * 64 + cl) * 3 + i]);
        }
    }

    for (int n = tid; n < NFFT; n += 128) {
        float a2 = (float)(2.0 * 3.14159265358979323846 / 256.0) * (float)n;
        float sn, cn;
        sincosf(a2, &sn, &cn);
        float win = 0.5f - 0.5f * cn;             // Hann
        int q = f * HOP + n - 128;
        int xi = q < 0 ? -q : (q >= LX ? (2 * LX - 2 - q) : q);  // reflect
        xw[n] = x[b * LX + xi] * win;
    }
    __syncthreads();

    const int k = tid;                            // bin 0..127
    float ang = (float)(2.0 * 3.14159265358979323846 / 256.0) * (float)k;
    float s1, c1;
    sincosf(ang, &s1, &c1);

    float A0 = 0.f, B0 = 0.f, A1 = 0.f, B1 = 0.f;
    float A2 = 0.f, B2 = 0.f, A3 = 0.f, B3 = 0.f;
    float c0 = 1.f, s0 = 0.f, cc1 = 1.f, ss1 = 0.f;
    float cc2 = 1.f, ss2 = 0.f, cc3 = 1.f, ss3 = 0.f;
    float rNe = 0.f, rNo = 0.f;

#pragma unroll 4
    for (int mq = 0; mq < 16; ++mq) {
        float4 v0 = *(const float4*)&xw[4 * mq];
        float4 v1 = *(const float4*)&xw[64 + 4 * mq];
        float4 v2 = *(const float4*)&xw[128 + 4 * mq];
        float4 v3 = *(const float4*)&xw[192 + 4 * mq];
        float e0[4] = {v0.x, v0.y, v0.z, v0.w};
        float e1[4] = {v1.x, v1.y, v1.z, v1.w};
        float e2[4] = {v2.x, v2.y, v2.z, v2.w};
        float e3[4] = {v3.x, v3.y, v3.z, v3.w};
#pragma unroll
        for (int mm = 0; mm < 4; ++mm) {
            float t;
            A0 = fmaf(e0[mm], c0, A0);  B0 = fmaf(e0[mm], s0, B0);
            A1 = fmaf(e1[mm], cc1, A1); B1 = fmaf(e1[mm], ss1, B1);
            A2 = fmaf(e2[mm], cc2, A2); B2 = fmaf(e2[mm], ss2, B2);
            A3 = fmaf(e3[mm], cc3, A3); B3 = fmaf(e3[mm], ss3, B3);
            if ((mm & 1) == 0) rNe += e0[mm] + e1[mm] + e2[mm] + e3[mm];
            else               rNo += e0[mm] + e1[mm] + e2[mm] + e3[mm];
            t = c0 * c1 - s0 * s1;   s0 = fmaf(c0, s1, s0 * c1);   c0 = t;
            t = cc1 * c1 - ss1 * s1; ss1 = fmaf(cc1, s1, ss1 * c1); cc1 = t;
            t = cc2 * c1 - ss2 * s1; ss2 = fmaf(cc2, s1, ss2 * c1); cc2 = t;
            t = cc3 * c1 - ss3 * s1; ss3 = fmaf(cc3, s1, ss3 * c1); cc3 = t;
        }
    }

    float re = A0, im = B0;
    float Aj[3] = {A1, A2, A3};
    float Bj[3] = {B1, B2, B3};
#pragma unroll
    for (int j = 1; j < 4; ++j) {
        int ph = (j * k) & 3;
        float cf = (ph == 0) ? 1.f : (ph == 2) ? -1.f : 0.f;
        float sf = (ph == 1) ? 1.f : (ph == 3) ? -1.f : 0.f;
        re += cf * Aj[j - 1] - sf * Bj[j - 1];
        im += sf * Aj[j - 1] + cf * Bj[j - 1];
    }

    float* prow = part + (b * NFRAMES + f) * PART_STRIDE;
    prow[k] = sqrtf(re * re + im * im);
    if (tid == 0) prow[128] = fabsf(rNe - rNo);
}

// ---------------- Gating MLP + top-2 softmax ----------------
__global__ __launch_bounds__(256) void gating_kernel(
    const float* __restrict__ part,
    const float* __restrict__ Wg1, const float* __restrict__ bg1,
    const float* __restrict__ Wg2, const float* __restrict__ bg2,
    const float* __restrict__ Wg3, const float* __restrict__ bg3,
    int* __restrict__ inds, float* __restrict__ wts) {
    __shared__ float pl[NBINS];
    __shared__ float h1[256];
    __shared__ float h2[128];
    __shared__ float lg[NE];
    const int b = blockIdx.x, tid = threadIdx.x;

    if (tid < NBINS) {
        float s = 0.f;
        for (int f = 0; f < NFRAMES; ++f)
            s += part[(b * NFRAMES + f) * PART_STRIDE + tid];
        pl[tid] = s * (1.0f / (float)NFRAMES);
    }
    __syncthreads();
    {
        float s = bg1[tid];
        for (int kk = 0; kk < NBINS; ++kk) s += pl[kk] * Wg1[kk * 256 + tid];
        h1[tid] = fmaxf(s, 0.f);
    }
    __syncthreads();
    if (tid < 128) {
        float s = bg2[tid];
        for (int kk = 0; kk < 256; ++kk) s += h1[kk] * Wg2[kk * 128 + tid];
        h2[tid] = fmaxf(s, 0.f);
    }
    __syncthreads();
    if (tid < NE) {
        float s = bg3[tid];
        for (int kk = 0; kk < 128; ++kk) s += h2[kk] * Wg3[kk * NE + tid];
        lg[tid] = s;
    }
    __syncthreads();
    if (tid == 0) {
        int i0 = 0;
        float v0 = lg[0];
        for (int i = 1; i < NE; ++i)
            if (lg[i] > v0) { v0 = lg[i]; i0 = i; }
        int i1 = -1;
        float v1 = -3.0e38f;
        for (int i = 0; i < NE; ++i) {
            if (i == i0) continue;
            if (lg[i] > v1) { v1 = lg[i]; i1 = i; }
        }
        float e1 = expf(v1 - v0);
        float w0 = 1.f / (1.f + e1);
        inds[b * 2 + 0] = i0;
        inds[b * 2 + 1] = i1;
        wts[b * 2 + 0] = w0;
        wts[b * 2 + 1] = e1 * w0;
    }
}

// ---------------- Expert path: fp32 conv1 -> bf16 MFMA conv2 ----------------
// grid (u-tiles=8 of 128, branch=3, batch=64), 512 threads (8 waves).
// MERGED SLOTS: phase A computes BOTH selected experts' h from one shared
// x window (2x ILP, x s_loads halved) into two LDS tiles; ONE barrier per
// block; phase C runs both slots' MFMA GEMMs back to back.
#define UT 128
#define HPR 68           // shorts per hp row (64 + 4 pad)
#define HROWS 258

template <int KSZ>
__device__ __attribute__((always_inline)) void expert_body(
    const float* __restrict__ x,
    const float* __restrict__ wa, const float* __restrict__ ba,
    const float* __restrict__ bb, const unsigned short* __restrict__ wTfbr,
    const int* __restrict__ inds, const float* __restrict__ wts,
    float* __restrict__ out, int br, short* hp0, short* hp1) {
    const int u0 = blockIdx.x * UT;
    const int b = blockIdx.z;
    const int tid = threadIdx.x;
    const int lane = tid & 63;
    const int quad = lane >> 4;
    const int l15 = lane & 15;
    const int wv = __builtin_amdgcn_readfirstlane(tid >> 6);
    const int mw = wv & 3;           // M-tile (c2 block of 16)
    const int nh = wv >> 2;          // N-half (4 N-tiles each)
    const int pad = KSZ >> 1;
    const int t0 = 2 * u0 - 1;
    const int x0 = 2 * t0 - pad;

    const float* xp = x + b * LX;

    const int e0 = __builtin_amdgcn_readfirstlane(inds[b * 2 + 0]);
    const int e1 = __builtin_amdgcn_readfirstlane(inds[b * 2 + 1]);
    const float wj0 = wts[b * 2 + 0];
    const float wj1 = wts[b * 2 + 1];

    // first-conv weights for this lane's channel (cl = lane), both experts
    float wr0[KSZ], wr1[KSZ];
#pragma unroll
    for (int i = 0; i < KSZ; ++i) {
        wr0[i] = wa[(e0 * NCH + lane) * KSZ + i];
        wr1[i] = wa[(e1 * NCH + lane) * KSZ + i];
    }
    const float bv0 = ba[e0 * NCH + lane];
    const float bv1 = ba[e1 * NCH + lane];

    // ---- phase A: rows 0..255 (8 uniform iters) + wv0 tail 256..257 ----
#pragma unroll 2
    for (int it = 0; it < 8; ++it) {
        int tb = wv + 8 * it;            // wave-uniform t-block (4 rows)
        int base = x0 + 8 * tb;          // wave-uniform -> s_load
        float xr[16];
        if (base >= 0 && base + 15 < LX) {
#pragma unroll
            for (int ii = 0; ii < 16; ++ii) xr[ii] = xp[base + ii];
        } else {
#pragma unroll
            for (int ii = 0; ii < 16; ++ii) {
                int xi = base + ii;
                xr[ii] = (xi >= 0 && xi < LX) ? xp[xi] : 0.f;
            }
        }
#pragma unroll
        for (int m = 0; m < 4; ++m) {
            int tl = 4 * tb + m;
            int t = t0 + tl;
            float s0v = bv0, s1v = bv1;
#pragma unroll
            for (int i = 0; i < KSZ; ++i) {
                s0v = fmaf(wr0[i], xr[2 * m + i], s0v);
                s1v = fmaf(wr1[i], xr[2 * m + i], s1v);
            }
            bool ok = (t >= 0 && t < LH);
            float h0 = ok ? fmaxf(s0v, 0.f) : 0.f;
            float h1 = ok ? fmaxf(s1v, 0.f) : 0.f;
            hp0[tl * HPR + lane] = (short)bf16r(h0);
            hp1[tl * HPR + lane] = (short)bf16r(h1);
        }
    }
    if (wv == 0) {
#pragma unroll
        for (int m = 0; m < 2; ++m) {
            int tl = 256 + m;
            int t = t0 + tl;
            int xb = x0 + 2 * tl;
            float s0v = bv0, s1v = bv1;
#pragma unroll
            for (int i = 0; i < KSZ; ++i) {
                int xi = xb + i;
                float xvv = (xi >= 0 && xi < LX) ? xp[xi] : 0.f;
                s0v = fmaf(wr0[i], xvv, s0v);
                s1v = fmaf(wr1[i], xvv, s1v);
            }
            bool ok = (t >= 0 && t < LH);
            hp0[tl * HPR + lane] = (short)bf16r(ok ? fmaxf(s0v, 0.f) : 0.f);
            hp1[tl * HPR + lane] = (short)bf16r(ok ? fmaxf(s1v, 0.f) : 0.f);
        }
    }
    __syncthreads();

    // ---- phase C: both slots' MFMA GEMMs ----
    float fin[4][4];
#pragma unroll
    for (int q = 0; q < 4; ++q)
#pragma unroll
        for (int r = 0; r < 4; ++r) fin[q][r] = 0.f;

#pragma unroll 1
    for (int slot = 0; slot < 2; ++slot) {
        const int e = slot ? e1 : e0;
        const float wj = slot ? wj1 : wj0;
        const short* hp = slot ? hp1 : hp0;

        float br4[4];
#pragma unroll
        for (int r = 0; r < 4; ++r)
            br4[r] = bb[e * NCH + mw * 16 + quad * 4 + r];

        short8 af[3][2];
        {
            const unsigned short* wbase =
                wTfbr + e * 12288 + mw * 3072 + lane * 8;
#pragma unroll
            for (int i = 0; i < 3; ++i)
#pragma unroll
                for (int kb = 0; kb < 2; ++kb)
                    af[i][kb] = *(const short8*)&wbase[i * 1024 + kb * 512];
        }

#pragma unroll 2
        for (int q = 0; q < 4; ++q) {
            int nt = nh * 4 + q;
            int nb = nt * 16 + l15;          // local u (B-layout n = lane&15)
            floatx4 acc = {br4[0], br4[1], br4[2], br4[3]};
#pragma unroll
            for (int i = 0; i < 3; ++i) {
                int tl = 2 * nb + i;         // B row
#pragma unroll
                for (int kb = 0; kb < 2; ++kb) {
                    int sb = tl * HPR + kb * 32 + quad * 8;
                    union { short8 v; unsigned long long q2[2]; } B;
                    B.q2[0] = *(const unsigned long long*)&hp[sb];
                    B.q2[1] = *(const unsigned long long*)&hp[sb + 4];
                    acc = __builtin_amdgcn_mfma_f32_16x16x32_bf16(
                        af[i][kb], B.v, acc, 0, 0, 0);
                }
            }
#pragma unroll
            for (int r = 0; r < 4; ++r)
                fin[q][r] += wj * fmaxf(acc[r], 0.f);
        }
    }

#pragma unroll
    for (int q = 0; q < 4; ++q) {
        int u = u0 + (nh * 4 + q) * 16 + l15;
#pragma unroll
        for (int r = 0; r < 4; ++r) {
            int c2 = mw * 16 + quad * 4 + r;
            out[(long)(b * 192 + br * 64 + c2) * LY + u] = fin[q][r];
        }
    }
}

__global__ __launch_bounds__(512, 2) void expert_kernel(
    const float* __restrict__ x,
    const float* __restrict__ wa3, const float* __restrict__ ba3,
    const float* __restrict__ bb3,
    const float* __restrict__ wa5, const float* __restrict__ ba5,
    const float* __restrict__ bb5,
    const float* __restrict__ wa7, const float* __restrict__ ba7,
    const float* __restrict__ bb7,
    const unsigned short* __restrict__ wTf,
    const int* __restrict__ inds, const float* __restrict__ wts,
    float* __restrict__ out) {
    __shared__ short hp0[HROWS * HPR];     // 35.1 KB
    __shared__ short hp1[HROWS * HPR];     // 35.1 KB (70.2 total, 2 blocks/CU)

    const int br = blockIdx.y;
    if (br == 0)
        expert_body<3>(x, wa3, ba3, bb3, wTf, inds, wts, out, 0, hp0, hp1);
    else if (br == 1)
        expert_body<5>(x, wa5, ba5, bb5, wTf + WTF_PER, inds, wts, out, 1,
                       hp0, hp1);
    else
        expert_body<7>(x, wa7, ba7, bb7, wTf + 2 * WTF_PER, inds, wts, out, 2,
                       hp0, hp1);
}

extern "C" void kernel_launch(void* const* d_in, const int* in_sizes, int n_in,
                              void* d_out, int out_size, void* d_ws, size_t ws_size,
                              hipStream_t stream) {
    const float* x   = (const float*)d_in[0];
    const float* Wg1 = (const float*)d_in[1];
    const float* bg1 = (const float*)d_in[2];
    const float* Wg2 = (const float*)d_in[3];
    const float* bg2 = (const float*)d_in[4];
    const float* Wg3 = (const float*)d_in[5];
    const float* bg3 = (const float*)d_in[6];
    const float* wa3 = (const float*)d_in[7];
    const float* ba3 = (const float*)d_in[8];
    const float* wb3 = (const float*)d_in[9];
    const float* bb3 = (const float*)d_in[10];
    const float* wa5 = (const float*)d_in[11];
    const float* ba5 = (const float*)d_in[12];
    const float* wb5 = (const float*)d_in[13];
    const float* bb5 = (const float*)d_in[14];
    const float* wa7 = (const float*)d_in[15];
    const float* ba7 = (const float*)d_in[16];
    const float* wb7 = (const float*)d_in[17];
    const float* bb7 = (const float*)d_in[18];

    float* part = (float*)d_ws;
    unsigned short* wTf = (unsigned short*)((char*)d_ws + WTF_OFF);
    int* inds = (int*)((char*)d_ws + IW_OFF);
    float* wts = (float*)((char*)d_ws + IW_OFF + 512);

    stft_kernel<<<dim3(NFRAMES, NB), 128, 0, stream>>>(x, wb3, wb5, wb7, wTf,
                                                       part);
    gating_kernel<<<NB, 256, 0, stream>>>(part, Wg1, bg1, Wg2, bg2, Wg3, bg3,
                                          inds, wts);
    expert_kernel<<<dim3(LY / UT, NBR, NB), 512, 0, stream>>>(
        x, wa3, ba3, bb3, wa5, ba5, bb5, wa7, ba7, bb7, wTf,
        inds, wts, (float*)d_out);
}

// Round 14
// 176.177 us; speedup vs baseline: 1.0501x; 1.0058x over previous
//
#include <hip/hip_runtime.h>
#include <math.h>

#define NFFT 256
#define NBINS 129
#define HOP 64
#define NFRAMES 65
#define NB 64
#define LX 4096
#define LH 2048
#define LY 1024
#define NCH 64
#define NBR 3
#define NE 8

#define PART_STRIDE 132
#define WTF_OFF 2197504             // bf16 A-fragment weights
#define WTF_PER 98304               // bf16 elements per branch
#define IW_OFF 2787328              // inds/wts

typedef __attribute__((ext_vector_type(8))) short short8;   // 8 bf16
typedef __attribute__((ext_vector_type(4))) float floatx4;

__device__ __forceinline__ unsigned short bf16r(float f) {  // round-nearest-even
    unsigned u = __builtin_bit_cast(unsigned, f);
    u += 0x7FFFu + ((u >> 16) & 1u);
    return (unsigned short)(u >> 16);
}

// ---------------- STFT: one frame/block + wTf gather ------------
// grid (65 frames, 64 batch), 128 threads. Direct row writes, no atomics.
__global__ __launch_bounds__(128) void stft_kernel(
    const float* __restrict__ x,
    const float* __restrict__ wb3, const float* __restrict__ wb5,
    const float* __restrict__ wb7, unsigned short* __restrict__ wTf,
    float* __restrict__ part) {
    __shared__ float xw[NFFT];
    const int f = blockIdx.x, b = blockIdx.y;
    const int tid = threadIdx.x;

    // one wTf element per thread (532k threads >= 295k elements)
    {
        int fi = (b * NFRAMES + f) * 128 + tid;
        if (fi < 3 * WTF_PER) {
            int br = fi / WTF_PER, r = fi % WTF_PER;
            int e = r / 12288;
            int r2 = r % 12288;
            int mw = r2 / 3072;
            int r3 = r2 % 3072;
            int i = r3 / 1024;
            int r4 = r3 % 1024;
            int kb = r4 / 512;
            int r5 = r4 % 512;
            int lane = r5 / 8, j = r5 % 8;
            int c2 = mw * 16 + (lane & 15);
            int cl = kb * 32 + (lane >> 4) * 8 + j;
            const float* src = (br == 0) ? wb3 : (br == 1) ? wb5 : wb7;
            wTf[fi] = bf16r(src[((e * 64 + c2) * 64 + cl) * 3 + i]);
        }
    }

    for (int n = tid; n < NFFT; n += 128) {
        float a2 = (float)(2.0 * 3.14159265358979323846 / 256.0) * (float)n;
        float sn, cn;
        sincosf(a2, &sn, &cn);
        float win = 0.5f - 0.5f * cn;             // Hann
        int q = f * HOP + n - 128;
        int xi = q < 0 ? -q : (q >= LX ? (2 * LX - 2 - q) : q);  // reflect
        xw[n] = x[b * LX + xi] * win;
    }
    __syncthreads();

    const int k = tid;                            // bin 0..127
    float ang = (float)(2.0 * 3.14159265358979323846 / 256.0) * (float)k;
    float s1, c1;
    sincosf(ang, &s1, &c1);

    float A0 = 0.f, B0 = 0.f, A1 = 0.f, B1 = 0.f;
    float A2 = 0.f, B2 = 0.f, A3 = 0.f, B3 = 0.f;
    float c0 = 1.f, s0 = 0.f, cc1 = 1.f, ss1 = 0.f;
    float cc2 = 1.f, ss2 = 0.f, cc3 = 1.f, ss3 = 0.f;
    float rNe = 0.f, rNo = 0.f;

#pragma unroll 4
    for (int mq = 0; mq < 16; ++mq) {
        float4 v0 = *(const float4*)&xw[4 * mq];
        float4 v1 = *(const float4*)&xw[64 + 4 * mq];
        float4 v2 = *(const float4*)&xw[128 + 4 * mq];
        float4 v3 = *(const float4*)&xw[192 + 4 * mq];
        float e0[4] = {v0.x, v0.y, v0.z, v0.w};
        float e1[4] = {v1.x, v1.y, v1.z, v1.w};
        float e2[4] = {v2.x, v2.y, v2.z, v2.w};
        float e3[4] = {v3.x, v3.y, v3.z, v3.w};
#pragma unroll
        for (int mm = 0; mm < 4; ++mm) {
            float t;
            A0 = fmaf(e0[mm], c0, A0);  B0 = fmaf(e0[mm], s0, B0);
            A1 = fmaf(e1[mm], cc1, A1); B1 = fmaf(e1[mm], ss1, B1);
            A2 = fmaf(e2[mm], cc2, A2); B2 = fmaf(e2[mm], ss2, B2);
            A3 = fmaf(e3[mm], cc3, A3); B3 = fmaf(e3[mm], ss3, B3);
            if ((mm & 1) == 0) rNe += e0[mm] + e1[mm] + e2[mm] + e3[mm];
            else               rNo += e0[mm] + e1[mm] + e2[mm] + e3[mm];
            t = c0 * c1 - s0 * s1;   s0 = fmaf(c0, s1, s0 * c1);   c0 = t;
            t = cc1 * c1 - ss1 * s1; ss1 = fmaf(cc1, s1, ss1 * c1); cc1 = t;
            t = cc2 * c1 - ss2 * s1; ss2 = fmaf(cc2, s1, ss2 * c1); cc2 = t;
            t = cc3 * c1 - ss3 * s1; ss3 = fmaf(cc3, s1, ss3 * c1); cc3 = t;
        }
    }

    float re = A0, im = B0;
    float Aj[3] = {A1, A2, A3};
    float Bj[3] = {B1, B2, B3};
#pragma unroll
    for (int j = 1; j < 4; ++j) {
        int ph = (j * k) & 3;
        float cf = (ph == 0) ? 1.f : (ph == 2) ? -1.f : 0.f;
        float sf = (ph == 1) ? 1.f : (ph == 3) ? -1.f : 0.f;
        re += cf * Aj[j - 1] - sf * Bj[j - 1];
        im += sf * Aj[j - 1] + cf * Bj[j - 1];
    }

    float* prow = part + (b * NFRAMES + f) * PART_STRIDE;
    prow[k] = sqrtf(re * re + im * im);
    if (tid == 0) prow[128] = fabsf(rNe - rNo);
}

// ---------------- Gating MLP + top-2 softmax ----------------
__global__ __launch_bounds__(256) void gating_kernel(
    const float* __restrict__ part,
    const float* __restrict__ Wg1, const float* __restrict__ bg1,
    const float* __restrict__ Wg2, const float* __restrict__ bg2,
    const float* __restrict__ Wg3, const float* __restrict__ bg3,
    int* __restrict__ inds, float* __restrict__ wts) {
    __shared__ float pl[NBINS];
    __shared__ float h1[256];
    __shared__ float h2[128];
    __shared__ float lg[NE];
    const int b = blockIdx.x, tid = threadIdx.x;

    if (tid < NBINS) {
        float s = 0.f;
        for (int f = 0; f < NFRAMES; ++f)
            s += part[(b * NFRAMES + f) * PART_STRIDE + tid];
        pl[tid] = s * (1.0f / (float)NFRAMES);
    }
    __syncthreads();
    {
        float s = bg1[tid];
        for (int kk = 0; kk < NBINS; ++kk) s += pl[kk] * Wg1[kk * 256 + tid];
        h1[tid] = fmaxf(s, 0.f);
    }
    __syncthreads();
    if (tid < 128) {
        float s = bg2[tid];
        for (int kk = 0; kk < 256; ++kk) s += h1[kk] * Wg2[kk * 128 + tid];
        h2[tid] = fmaxf(s, 0.f);
    }
    __syncthreads();
    if (tid < NE) {
        float s = bg3[tid];
        for (int kk = 0; kk < 128; ++kk) s += h2[kk] * Wg3[kk * NE + tid];
        lg[tid] = s;
    }
    __syncthreads();
    if (tid == 0) {
        int i0 = 0;
        float v0 = lg[0];
        for (int i = 1; i < NE; ++i)
            if (lg[i] > v0) { v0 = lg[i]; i0 = i; }
        int i1 = -1;
        float v1 = -3.0e38f;
        for (int i = 0; i < NE; ++i) {
            if (i == i0) continue;
            if (lg[i] > v1) { v1 = lg[i]; i1 = i; }
        }
        float e1 = expf(v1 - v0);
        float w0 = 1.f / (1.f + e1);
        inds[b * 2 + 0] = i0;
        inds[b * 2 + 1] = i1;
        wts[b * 2 + 0] = w0;
        wts[b * 2 + 1] = e1 * w0;
    }
}

// ---------------- Expert path: fp32 conv1 -> bf16 MFMA conv2 ----------------
// grid (u-tiles=8 of 128, branch=3, batch=64), 512 threads (8 waves).
// x segment staged to LDS once (coalesced); phase A reads are same-address
// LDS broadcasts (conflict-exempt) -> no in-loop global latency. Merged
// slots: both experts' h from one x read, two LDS tiles, one barrier pair.
#define UT 128
#define HPR 68           // shorts per hp row (64 + 4 pad)
#define HROWS 258
#define XLN 524          // staged x floats (max used 514+KSZ=521)

template <int KSZ>
__device__ __attribute__((always_inline)) void expert_body(
    const float* __restrict__ x,
    const float* __restrict__ wa, const float* __restrict__ ba,
    const float* __restrict__ bb, const unsigned short* __restrict__ wTfbr,
    const int* __restrict__ inds, const float* __restrict__ wts,
    float* __restrict__ out, int br, short* hp0, short* hp1, float* xl) {
    const int u0 = blockIdx.x * UT;
    const int b = blockIdx.z;
    const int tid = threadIdx.x;
    const int lane = tid & 63;
    const int quad = lane >> 4;
    const int l15 = lane & 15;
    const int wv = __builtin_amdgcn_readfirstlane(tid >> 6);
    const int mw = wv & 3;           // M-tile (c2 block of 16)
    const int nh = wv >> 2;          // N-half (4 N-tiles each)
    const int pad = KSZ >> 1;
    const int t0 = 2 * u0 - 1;
    const int x0 = 2 * t0 - pad;

    const float* xp = x + b * LX;

    const int e0 = __builtin_amdgcn_readfirstlane(inds[b * 2 + 0]);
    const int e1 = __builtin_amdgcn_readfirstlane(inds[b * 2 + 1]);
    const float wj0 = wts[b * 2 + 0];
    const float wj1 = wts[b * 2 + 1];

    // stage x segment (zero-padded) into LDS, coalesced
    for (int j = tid; j < 514 + KSZ; j += 512) {
        int xi = x0 + j;
        xl[j] = (xi >= 0 && xi < LX) ? xp[xi] : 0.f;
    }

    // first-conv weights for this lane's channel (cl = lane), both experts
    float wr0[KSZ], wr1[KSZ];
#pragma unroll
    for (int i = 0; i < KSZ; ++i) {
        wr0[i] = wa[(e0 * NCH + lane) * KSZ + i];
        wr1[i] = wa[(e1 * NCH + lane) * KSZ + i];
    }
    const float bv0 = ba[e0 * NCH + lane];
    const float bv1 = ba[e1 * NCH + lane];

    __syncthreads();   // xl ready

    // ---- phase A: rows 0..255 (8 uniform iters) + wv0 tail 256..257 ----
#pragma unroll 2
    for (int it = 0; it < 8; ++it) {
        int tb = wv + 8 * it;            // wave-uniform t-block (4 rows)
        float4 xv0 = *(const float4*)&xl[8 * tb + 0];    // broadcast reads
        float4 xv1 = *(const float4*)&xl[8 * tb + 4];
        float4 xv2 = *(const float4*)&xl[8 * tb + 8];
        float4 xv3 = *(const float4*)&xl[8 * tb + 12];
        float xr[16] = {xv0.x, xv0.y, xv0.z, xv0.w,
                        xv1.x, xv1.y, xv1.z, xv1.w,
                        xv2.x, xv2.y, xv2.z, xv2.w,
                        xv3.x, xv3.y, xv3.z, xv3.w};
#pragma unroll
        for (int m = 0; m < 4; ++m) {
            int tl = 4 * tb + m;
            int t = t0 + tl;
            float s0v = bv0, s1v = bv1;
#pragma unroll
            for (int i = 0; i < KSZ; ++i) {
                s0v = fmaf(wr0[i], xr[2 * m + i], s0v);
                s1v = fmaf(wr1[i], xr[2 * m + i], s1v);
            }
            bool ok = (t >= 0 && t < LH);
            float h0 = ok ? fmaxf(s0v, 0.f) : 0.f;
            float h1 = ok ? fmaxf(s1v, 0.f) : 0.f;
            hp0[tl * HPR + lane] = (short)bf16r(h0);
            hp1[tl * HPR + lane] = (short)bf16r(h1);
        }
    }
    if (wv == 0) {
#pragma unroll
        for (int m = 0; m < 2; ++m) {
            int tl = 256 + m;
            int t = t0 + tl;
            float s0v = bv0, s1v = bv1;
#pragma unroll
            for (int i = 0; i < KSZ; ++i) {
                float xvv = xl[2 * tl + i];
                s0v = fmaf(wr0[i], xvv, s0v);
                s1v = fmaf(wr1[i], xvv, s1v);
            }
            bool ok = (t >= 0 && t < LH);
            hp0[tl * HPR + lane] = (short)bf16r(ok ? fmaxf(s0v, 0.f) : 0.f);
            hp1[tl * HPR + lane] = (short)bf16r(ok ? fmaxf(s1v, 0.f) : 0.f);
        }
    }
    __syncthreads();

    // ---- phase C: both slots' MFMA GEMMs ----
    float fin[4][4];
#pragma unroll
    for (int q = 0; q < 4; ++q)
#pragma unroll
        for (int r = 0; r < 4; ++r) fin[q][r] = 0.f;

#pragma unroll 1
    for (int slot = 0; slot < 2; ++slot) {
        const int e = slot ? e1 : e0;
        const float wj = slot ? wj1 : wj0;
        const short* hp = slot ? hp1 : hp0;

        float br4[4];
#pragma unroll
        for (int r = 0; r < 4; ++r)
            br4[r] = bb[e * NCH + mw * 16 + quad * 4 + r];

        short8 af[3][2];
        {
            const unsigned short* wbase =
                wTfbr + e * 12288 + mw * 3072 + lane * 8;
#pragma unroll
            for (int i = 0; i < 3; ++i)
#pragma unroll
                for (int kb = 0; kb < 2; ++kb)
                    af[i][kb] = *(const short8*)&wbase[i * 1024 + kb * 512];
        }

#pragma unroll 2
        for (int q = 0; q < 4; ++q) {
            int nt = nh * 4 + q;
            int nb = nt * 16 + l15;          // local u (B-layout n = lane&15)
            floatx4 acc = {br4[0], br4[1], br4[2], br4[3]};
#pragma unroll
            for (int i = 0; i < 3; ++i) {
                int tl = 2 * nb + i;         // B row
#pragma unroll
                for (int kb = 0; kb < 2; ++kb) {
                    int sb = tl * HPR + kb * 32 + quad * 8;
                    union { short8 v; unsigned long long q2[2]; } B;
                    B.q2[0] = *(const unsigned long long*)&hp[sb];
                    B.q2[1] = *(const unsigned long long*)&hp[sb + 4];
                    acc = __builtin_amdgcn_mfma_f32_16x16x32_bf16(
                        af[i][kb], B.v, acc, 0, 0, 0);
                }
            }
#pragma unroll
            for (int r = 0; r < 4; ++r)
                fin[q][r] += wj * fmaxf(acc[r], 0.f);
        }
    }

#pragma unroll
    for (int q = 0; q < 4; ++q) {
        int u = u0 + (nh * 4 + q) * 16 + l15;
#pragma unroll
        for (int r = 0; r < 4; ++r) {
            int c2 = mw * 16 + quad * 4 + r;
            out[(long)(b * 192 + br * 64 + c2) * LY + u] = fin[q][r];
        }
    }
}

__global__ __launch_bounds__(512, 2) void expert_kernel(
    const float* __restrict__ x,
    const float* __restrict__ wa3, const float* __restrict__ ba3,
    const float* __restrict__ bb3,
    const float* __restrict__ wa5, const float* __restrict__ ba5,
    const float* __restrict__ bb5,
    const float* __restrict__ wa7, const float* __restrict__ ba7,
    const float* __restrict__ bb7,
    const unsigned short* __restrict__ wTf,
    const int* __restrict__ inds, const float* __restrict__ wts,
    float* __restrict__ out) {
    __shared__ short hp0[HROWS * HPR];     // 35.1 KB
    __shared__ short hp1[HROWS * HPR];     // 35.1 KB
    __shared__ float xl[XLN];              // 2.1 KB (72.3 total, 2 blocks/CU)

    const int br = blockIdx.y;
    if (br == 0)
        expert_body<3>(x, wa3, ba3, bb3, wTf, inds, wts, out, 0, hp0, hp1, xl);
    else if (br == 1)
        expert_body<5>(x, wa5, ba5, bb5, wTf + WTF_PER, inds, wts, out, 1,
                       hp0, hp1, xl);
    else
        expert_body<7>(x, wa7, ba7, bb7, wTf + 2 * WTF_PER, inds, wts, out, 2,
                       hp0, hp1, xl);
}

extern "C" void kernel_launch(void* const* d_in, const int* in_sizes, int n_in,
                              void* d_out, int out_size, void* d_ws, size_t ws_size,
                              hipStream_t stream) {
    const float* x   = (const float*)d_in[0];
    const float* Wg1 = (const float*)d_in[1];
    const float* bg1 = (const float*)d_in[2];
    const float* Wg2 = (const float*)d_in[3];
    const float* bg2 = (const float*)d_in[4];
    const float* Wg3 = (const float*)d_in[5];
    const float* bg3 = (const float*)d_in[6];
    const float* wa3 = (const float*)d_in[7];
    const float* ba3 = (const float*)d_in[8];
    const float* wb3 = (const float*)d_in[9];
    const float* bb3 = (const float*)d_in[10];
    const float* wa5 = (const float*)d_in[11];
    const float* ba5 = (const float*)d_in[12];
    const float* wb5 = (const float*)d_in[13];
    const float* bb5 = (const float*)d_in[14];
    const float* wa7 = (const float*)d_in[15];
    const float* ba7 = (const float*)d_in[16];
    const float* wb7 = (const float*)d_in[17];
    const float* bb7 = (const float*)d_in[18];

    float* part = (float*)d_ws;
    unsigned short* wTf = (unsigned short*)((char*)d_ws + WTF_OFF);
    int* inds = (int*)((char*)d_ws + IW_OFF);
    float* wts = (float*)((char*)d_ws + IW_OFF + 512);

    stft_kernel<<<dim3(NFRAMES, NB), 128, 0, stream>>>(x, wb3, wb5, wb7, wTf,
                                                       part);
    gating_kernel<<<NB, 256, 0, stream>>>(part, Wg1, bg1, Wg2, bg2, Wg3, bg3,
                                          inds, wts);
    expert_kernel<<<dim3(LY / UT, NBR, NB), 512, 0, stream>>>(
        x, wa3, ba3, bb3, wa5, ba5, bb5, wa7, ba7, bb7, wTf,
        inds, wts, (float*)d_out);
}